// Round 1
// baseline (472.265 us; speedup 1.0000x reference)
//
#include <hip/hip_runtime.h>
#include <math.h>

#define SEQ 4096
#define CH  256
#define NHT 8      // N * HEADS
#define DHD 64

using bf16x8 = __attribute__((ext_vector_type(8))) short;
using f32x4  = __attribute__((ext_vector_type(4))) float;
typedef unsigned short u16;
typedef unsigned int   u32;

__device__ __forceinline__ u16 f2bf(float f) {
    u32 u = __float_as_uint(f);
    u = (u + 0x7fffu + ((u >> 16) & 1u)) >> 16;
    return (u16)u;
}
__device__ __forceinline__ float bf2f(u16 h) {
    return __uint_as_float(((u32)h) << 16);
}

// ---------------------------------------------------------------------------
// Core: 128x128 NT GEMM tile. A [128 rows][K] row-major bf16 (lda), Bt [128
// rows=out-cols][K] row-major bf16 (ldb). 256 threads = 4 waves; wave w owns a
// 64x64 quadrant (rows (w>>1)*64.., cols (w&1)*64..). acc[i][j] is 16x16 MFMA
// C-layout: C[wr+i*16+quad*4+r][wc+j*16+(lane&15)].
// ---------------------------------------------------------------------------
__device__ __forceinline__ void mm128(const u16* __restrict__ Arow, int lda,
                                      const u16* __restrict__ Brow, int ldb,
                                      int K, u16 (*lA)[40], u16 (*lB)[40],
                                      f32x4 acc[4][4])
{
    const int t    = threadIdx.x;
    const int wave = t >> 6, lane = t & 63;
    const int quad = lane >> 4, l16 = lane & 15;
    const int wr = (wave >> 1) * 64, wc = (wave & 1) * 64;
    const int lrow = t >> 2;          // 0..63
    const int lcol = (t & 3) * 8;     // 0,8,16,24

    for (int kt = 0; kt < K; kt += 32) {
        *(uint4*)&lA[lrow][lcol]      = *(const uint4*)&Arow[lrow * lda + kt + lcol];
        *(uint4*)&lA[lrow + 64][lcol] = *(const uint4*)&Arow[(lrow + 64) * lda + kt + lcol];
        *(uint4*)&lB[lrow][lcol]      = *(const uint4*)&Brow[lrow * ldb + kt + lcol];
        *(uint4*)&lB[lrow + 64][lcol] = *(const uint4*)&Brow[(lrow + 64) * ldb + kt + lcol];
        __syncthreads();
        bf16x8 af[4], bf[4];
        #pragma unroll
        for (int i = 0; i < 4; i++) af[i] = *(const bf16x8*)&lA[wr + i * 16 + l16][quad * 8];
        #pragma unroll
        for (int j = 0; j < 4; j++) bf[j] = *(const bf16x8*)&lB[wc + j * 16 + l16][quad * 8];
        #pragma unroll
        for (int i = 0; i < 4; i++)
            #pragma unroll
            for (int j = 0; j < 4; j++)
                acc[i][j] = __builtin_amdgcn_mfma_f32_16x16x32_bf16(af[i], bf[j], acc[i][j], 0, 0, 0);
        __syncthreads();
    }
}

// ---------------------------------------------------------------------------
// Pack weights, transposed for NT GEMM. BtQKV[j][c] (j: 0..255 Q,256..511 K,
// 512..767 V; within 256: h*64+d). W1t[j][c]=W1[c][j], W2t likewise.
// ---------------------------------------------------------------------------
__global__ __launch_bounds__(256) void k_pack(const float* __restrict__ WQ,
                                              const float* __restrict__ WK,
                                              const float* __restrict__ WV,
                                              const float* __restrict__ W1,
                                              const float* __restrict__ W2,
                                              u16* __restrict__ BtQKV,
                                              u16* __restrict__ W1t,
                                              u16* __restrict__ W2t)
{
    int id = blockIdx.x * 256 + threadIdx.x;
    if (id < 768 * 256) {
        int j = id >> 8, c = id & 255;
        int which = j >> 8, h = (j >> 6) & 3, d = j & 63;
        const float* W = (which == 0) ? WQ : (which == 1) ? WK : WV;
        BtQKV[id] = f2bf(W[(h * 256 + c) * 64 + d]);
    } else if (id < 768 * 256 + 65536) {
        int jj = id - 768 * 256;
        int j = jj >> 8, c = jj & 255;
        W1t[jj] = f2bf(W1[c * 256 + j]);
    } else if (id < 768 * 256 + 2 * 65536) {
        int jj = id - 768 * 256 - 65536;
        int j = jj >> 8, c = jj & 255;
        W2t[jj] = f2bf(W2[c * 256 + j]);
    }
}

// ---------------------------------------------------------------------------
// LN1: x [N][C][S] -> norm bf16 [N][S][C].  32 s-rows per block via LDS tile.
// ---------------------------------------------------------------------------
__global__ __launch_bounds__(256) void k_ln1(const float* __restrict__ x,
                                             const float* __restrict__ w,
                                             const float* __restrict__ b,
                                             u16* __restrict__ norm)
{
    __shared__ float tile[32][257];
    __shared__ float mu[32], rs[32];
    int n = blockIdx.y, s0 = blockIdx.x * 32;
    int t = threadIdx.x;
    int sl = t & 31, cg = t >> 5;          // 8 c per pass
    for (int cc = 0; cc < 256; cc += 8) {
        int c = cc + cg;
        tile[sl][c] = x[(n * 256 + c) * SEQ + s0 + sl];
    }
    __syncthreads();
    int wv = t >> 6, l = t & 63;
    for (int rr = 0; rr < 8; rr++) {
        int s = wv * 8 + rr;
        float a0 = tile[s][l], a1 = tile[s][l + 64], a2 = tile[s][l + 128], a3 = tile[s][l + 192];
        float sm = a0 + a1 + a2 + a3;
        float sq = a0 * a0 + a1 * a1 + a2 * a2 + a3 * a3;
        for (int off = 32; off; off >>= 1) { sm += __shfl_xor(sm, off); sq += __shfl_xor(sq, off); }
        if (l == 0) {
            float m = sm * (1.f / 256.f);
            mu[s] = m;
            rs[s] = rsqrtf(sq * (1.f / 256.f) - m * m + 1e-5f);
        }
    }
    __syncthreads();
    float ww = w[t & 255], bb = b[t & 255];
    for (int s = 0; s < 32; s++) {
        float v = (tile[s][t] - mu[s]) * rs[s] * ww + bb;
        norm[(n * SEQ + s0 + s) * 256 + t] = f2bf(v);
    }
}

// ---------------------------------------------------------------------------
// QKV projection: norm [8192][256] @ BtQKV^T -> Q,K,V bf16 [NHT][SEQ][64].
// ---------------------------------------------------------------------------
__global__ __launch_bounds__(256) void k_qkv(const u16* __restrict__ norm,
                                             const u16* __restrict__ Bt,
                                             u16* __restrict__ Qo,
                                             u16* __restrict__ Ko,
                                             u16* __restrict__ Vo)
{
    __shared__ __align__(16) u16 lA[128][40];
    __shared__ __align__(16) u16 lB[128][40];
    int j0 = blockIdx.x * 128, m0 = blockIdx.y * 128;
    f32x4 z = {0.f, 0.f, 0.f, 0.f};
    f32x4 acc[4][4];
    #pragma unroll
    for (int i = 0; i < 4; i++)
        #pragma unroll
        for (int j = 0; j < 4; j++) acc[i][j] = z;
    mm128(norm + (long)m0 * 256, 256, Bt + (long)j0 * 256, 256, 256, lA, lB, acc);
    int t = threadIdx.x, wave = t >> 6, lane = t & 63, quad = lane >> 4, l16 = lane & 15;
    int wr = (wave >> 1) * 64, wc = (wave & 1) * 64;
    #pragma unroll
    for (int i = 0; i < 4; i++)
        #pragma unroll
        for (int j = 0; j < 4; j++) {
            int col = j0 + wc + j * 16 + l16;
            int which = col >> 8, h = (col >> 6) & 3, d = col & 63;
            u16* dst = (which == 0) ? Qo : (which == 1) ? Ko : Vo;
            #pragma unroll
            for (int r = 0; r < 4; r++) {
                int m = m0 + wr + i * 16 + quad * 4 + r;
                int n = m >> 12, s = m & 4095;
                dst[((n * 4 + h) * SEQ + s) * 64 + d] = f2bf(acc[i][j][r]);
            }
        }
}

// ---------------------------------------------------------------------------
// Pass 1: D[nh][k] = sum_q exp(Q·K^T / 64). One block per (nh, 128 k-cols),
// loops all q internally -> no global atomics.
// ---------------------------------------------------------------------------
__global__ __launch_bounds__(256) void k_pass1(const u16* __restrict__ Q,
                                               const u16* __restrict__ Km,
                                               float* __restrict__ D)
{
    __shared__ __align__(16) u16 lA[128][40];
    __shared__ __align__(16) u16 lB[128][40];
    __shared__ float colsum[128];
    int nh = blockIdx.y, k0 = blockIdx.x * 128;
    const u16* Qh = Q + (long)nh * SEQ * 64;
    const u16* Kh = Km + (long)nh * SEQ * 64;
    int t = threadIdx.x;
    if (t < 128) colsum[t] = 0.f;
    __syncthreads();
    int wave = t >> 6, lane = t & 63, quad = lane >> 4, l16 = lane & 15;
    int wc = (wave & 1) * 64;
    f32x4 z = {0.f, 0.f, 0.f, 0.f};
    for (int q0 = 0; q0 < SEQ; q0 += 128) {
        f32x4 acc[4][4];
        #pragma unroll
        for (int i = 0; i < 4; i++)
            #pragma unroll
            for (int j = 0; j < 4; j++) acc[i][j] = z;
        mm128(Qh + q0 * 64, 64, Kh + k0 * 64, 64, 64, lA, lB, acc);
        #pragma unroll
        for (int j = 0; j < 4; j++) {
            float p = 0.f;
            #pragma unroll
            for (int i = 0; i < 4; i++)
                #pragma unroll
                for (int r = 0; r < 4; r++) p += expf(acc[i][j][r] * 0.015625f);
            p += __shfl_xor(p, 16);
            p += __shfl_xor(p, 32);
            if (quad == 0) atomicAdd(&colsum[wc + j * 16 + l16], p);
        }
    }
    __syncthreads();
    if (t < 128) D[nh * SEQ + k0 + t] = colsum[t];
}

// ---------------------------------------------------------------------------
// Scale+transpose V: Vt[nh][d][k] = V[nh][k][d] / D[nh][k]  (bf16).
// ---------------------------------------------------------------------------
__global__ __launch_bounds__(256) void k_scaleV(const u16* __restrict__ V,
                                                const float* __restrict__ D,
                                                u16* __restrict__ Vt)
{
    __shared__ float tile[64][65];
    int nh = blockIdx.y, k0 = blockIdx.x * 64;
    int t = threadIdx.x;
    int d = t & 63, kk = t >> 6;
    const u16* Vh = V + (long)nh * SEQ * 64;
    const float* Dh = D + nh * SEQ;
    for (int p = 0; p < 16; p++) {
        int k = p * 4 + kk;
        tile[k][d] = bf2f(Vh[(k0 + k) * 64 + d]) * (1.f / Dh[k0 + k]);
    }
    __syncthreads();
    int k2 = t & 63, d4 = t >> 6;
    u16* Vth = Vt + (long)nh * 64 * SEQ;
    for (int p = 0; p < 16; p++) {
        int dd = p * 4 + d4;
        Vth[dd * SEQ + k0 + k2] = f2bf(tile[k2][dd]);
    }
}

// ---------------------------------------------------------------------------
// Pass 2: attn = exp(QK^T/64) @ Vt'.  Block per (nh, 128 q). For each k-tile:
// P tile via mm128, exp -> bf16 -> lP; V' tile -> lV (aliases lA/lB, safe: mm128
// is done with them); then accO += P@V'. Epilogue writes attn_cat fp32 [N][S][C].
// ---------------------------------------------------------------------------
__global__ __launch_bounds__(256) void k_pass2(const u16* __restrict__ Q,
                                               const u16* __restrict__ Km,
                                               const u16* __restrict__ Vt,
                                               float* __restrict__ attn_cat)
{
    __shared__ __align__(16) u16 smem[128 * 40 * 2];   // lA | lB, lV aliases
    __shared__ __align__(16) u16 lP[128][136];
    u16 (*lA)[40]  = (u16(*)[40])smem;
    u16 (*lB)[40]  = (u16(*)[40])(smem + 128 * 40);
    u16 (*lV)[136] = (u16(*)[136])smem;

    int nh = blockIdx.y, q0 = blockIdx.x * 128;
    int n = nh >> 2, h = nh & 3;
    const u16* Qh = Q + (long)nh * SEQ * 64;
    const u16* Kh = Km + (long)nh * SEQ * 64;
    const u16* Vh = Vt + (long)nh * 64 * SEQ;
    int t = threadIdx.x, wave = t >> 6, lane = t & 63, quad = lane >> 4, l16 = lane & 15;
    int wr = (wave >> 1) * 64, wc = (wave & 1) * 64;
    f32x4 z = {0.f, 0.f, 0.f, 0.f};
    f32x4 accO[2][4];
    #pragma unroll
    for (int i = 0; i < 2; i++)
        #pragma unroll
        for (int j = 0; j < 4; j++) accO[i][j] = z;

    for (int k0 = 0; k0 < SEQ; k0 += 128) {
        f32x4 acc[4][4];
        #pragma unroll
        for (int i = 0; i < 4; i++)
            #pragma unroll
            for (int j = 0; j < 4; j++) acc[i][j] = z;
        mm128(Qh + q0 * 64, 64, Kh + k0 * 64, 64, 64, lA, lB, acc);
        // P -> lP (bf16). lA/lB free after mm128; load V' tile into lV.
        #pragma unroll
        for (int i = 0; i < 4; i++)
            #pragma unroll
            for (int j = 0; j < 4; j++)
                #pragma unroll
                for (int r = 0; r < 4; r++) {
                    int row = wr + i * 16 + quad * 4 + r;
                    int col = wc + j * 16 + l16;
                    lP[row][col] = f2bf(expf(acc[i][j][r] * 0.015625f));
                }
        {
            int rr = t >> 4;            // 0..15
            int kc = (t & 15) * 8;      // 0..120
            for (int p = 0; p < 4; p++)
                *(uint4*)&lV[rr + p * 16][kc] = *(const uint4*)&Vh[(rr + p * 16) * SEQ + k0 + kc];
        }
        __syncthreads();
        #pragma unroll
        for (int kk = 0; kk < 128; kk += 32) {
            bf16x8 pa[2], vb[4];
            #pragma unroll
            for (int i = 0; i < 2; i++) pa[i] = *(const bf16x8*)&lP[wave * 32 + i * 16 + l16][quad * 8 + kk];
            #pragma unroll
            for (int j = 0; j < 4; j++) vb[j] = *(const bf16x8*)&lV[j * 16 + l16][quad * 8 + kk];
            #pragma unroll
            for (int i = 0; i < 2; i++)
                #pragma unroll
                for (int j = 0; j < 4; j++)
                    accO[i][j] = __builtin_amdgcn_mfma_f32_16x16x32_bf16(pa[i], vb[j], accO[i][j], 0, 0, 0);
        }
        __syncthreads();
    }
    #pragma unroll
    for (int i = 0; i < 2; i++)
        #pragma unroll
        for (int j = 0; j < 4; j++)
            #pragma unroll
            for (int r = 0; r < 4; r++) {
                int s = q0 + wave * 32 + i * 16 + quad * 4 + r;
                int c = h * 64 + j * 16 + l16;
                attn_cat[((long)n * SEQ + s) * 256 + c] = accO[i][j][r];
            }
}

// ---------------------------------------------------------------------------
// LN2: h2 = LN(attn_cat + x^T) bf16 [N][S][C].
// ---------------------------------------------------------------------------
__global__ __launch_bounds__(256) void k_ln2(const float* __restrict__ x,
                                             const float* __restrict__ attn_cat,
                                             const float* __restrict__ w,
                                             const float* __restrict__ b,
                                             u16* __restrict__ h2)
{
    __shared__ float tile[32][257];
    __shared__ float mu[32], rs[32];
    int n = blockIdx.y, s0 = blockIdx.x * 32;
    int t = threadIdx.x;
    int sl = t & 31, cg = t >> 5;
    for (int cc = 0; cc < 256; cc += 8) {
        int c = cc + cg;
        tile[sl][c] = x[(n * 256 + c) * SEQ + s0 + sl];
    }
    __syncthreads();
    for (int s = 0; s < 32; s++)
        tile[s][t] += attn_cat[((long)n * SEQ + s0 + s) * 256 + t];
    __syncthreads();
    int wv = t >> 6, l = t & 63;
    for (int rr = 0; rr < 8; rr++) {
        int s = wv * 8 + rr;
        float a0 = tile[s][l], a1 = tile[s][l + 64], a2 = tile[s][l + 128], a3 = tile[s][l + 192];
        float sm = a0 + a1 + a2 + a3;
        float sq = a0 * a0 + a1 * a1 + a2 * a2 + a3 * a3;
        for (int off = 32; off; off >>= 1) { sm += __shfl_xor(sm, off); sq += __shfl_xor(sq, off); }
        if (l == 0) {
            float m = sm * (1.f / 256.f);
            mu[s] = m;
            rs[s] = rsqrtf(sq * (1.f / 256.f) - m * m + 1e-5f);
        }
    }
    __syncthreads();
    float ww = w[t], bb = b[t];
    for (int s = 0; s < 32; s++) {
        float v = (tile[s][t] - mu[s]) * rs[s] * ww + bb;
        h2[((long)n * SEQ + s0 + s) * 256 + t] = f2bf(v);
    }
}

// ---------------------------------------------------------------------------
// MLP1: t = gelu(h2 @ W1 + b1) bf16.
// ---------------------------------------------------------------------------
__global__ __launch_bounds__(256) void k_mlp1(const u16* __restrict__ h2,
                                              const u16* __restrict__ W1t,
                                              const float* __restrict__ b1,
                                              u16* __restrict__ tbuf)
{
    __shared__ __align__(16) u16 lA[128][40];
    __shared__ __align__(16) u16 lB[128][40];
    int j0 = blockIdx.x * 128, m0 = blockIdx.y * 128;
    f32x4 z = {0.f, 0.f, 0.f, 0.f};
    f32x4 acc[4][4];
    #pragma unroll
    for (int i = 0; i < 4; i++)
        #pragma unroll
        for (int j = 0; j < 4; j++) acc[i][j] = z;
    mm128(h2 + (long)m0 * 256, 256, W1t + (long)j0 * 256, 256, 256, lA, lB, acc);
    int t = threadIdx.x, wave = t >> 6, lane = t & 63, quad = lane >> 4, l16 = lane & 15;
    int wr = (wave >> 1) * 64, wc = (wave & 1) * 64;
    #pragma unroll
    for (int i = 0; i < 4; i++)
        #pragma unroll
        for (int j = 0; j < 4; j++) {
            int col = j0 + wc + j * 16 + l16;
            float bj = b1[col];
            #pragma unroll
            for (int r = 0; r < 4; r++) {
                int m = m0 + wr + i * 16 + quad * 4 + r;
                float v = acc[i][j][r] + bj;
                float g = 0.5f * v * (1.f + erff(v * 0.70710678118f));
                tbuf[(long)m * 256 + col] = f2bf(g);
            }
        }
}

// ---------------------------------------------------------------------------
// MLP2 + final residual: osc = tbuf @ W2 + b2 + attn_cat  (fp32 [N][S][C]).
// ---------------------------------------------------------------------------
__global__ __launch_bounds__(256) void k_mlp2(const u16* __restrict__ tbuf,
                                              const u16* __restrict__ W2t,
                                              const float* __restrict__ b2,
                                              const float* __restrict__ attn_cat,
                                              float* __restrict__ osc)
{
    __shared__ __align__(16) u16 lA[128][40];
    __shared__ __align__(16) u16 lB[128][40];
    int j0 = blockIdx.x * 128, m0 = blockIdx.y * 128;
    f32x4 z = {0.f, 0.f, 0.f, 0.f};
    f32x4 acc[4][4];
    #pragma unroll
    for (int i = 0; i < 4; i++)
        #pragma unroll
        for (int j = 0; j < 4; j++) acc[i][j] = z;
    mm128(tbuf + (long)m0 * 256, 256, W2t + (long)j0 * 256, 256, 256, lA, lB, acc);
    int t = threadIdx.x, wave = t >> 6, lane = t & 63, quad = lane >> 4, l16 = lane & 15;
    int wr = (wave >> 1) * 64, wc = (wave & 1) * 64;
    #pragma unroll
    for (int i = 0; i < 4; i++)
        #pragma unroll
        for (int j = 0; j < 4; j++) {
            int col = j0 + wc + j * 16 + l16;
            float bj = b2[col];
            #pragma unroll
            for (int r = 0; r < 4; r++) {
                int m = m0 + wr + i * 16 + quad * 4 + r;
                osc[(long)m * 256 + col] = acc[i][j][r] + bj + attn_cat[(long)m * 256 + col];
            }
        }
}

// ---------------------------------------------------------------------------
// Final transpose: osc [N][S][C] -> out [N][C][S].
// ---------------------------------------------------------------------------
__global__ __launch_bounds__(256) void k_trout(const float* __restrict__ osc,
                                               float* __restrict__ out)
{
    __shared__ float tile[64][65];
    int n = blockIdx.z, c0 = blockIdx.y * 64, s0 = blockIdx.x * 64;
    int t = threadIdx.x;
    int cc = t & 63, s4 = t >> 6;
    for (int p = 0; p < 16; p++) {
        int s = p * 4 + s4;
        tile[s][cc] = osc[((long)n * SEQ + s0 + s) * 256 + c0 + cc];
    }
    __syncthreads();
    int ss = t & 63, c4 = t >> 6;
    for (int p = 0; p < 16; p++) {
        int c = p * 4 + c4;
        out[((long)n * 256 + c0 + c) * SEQ + s0 + ss] = tile[ss][c];
    }
}

// ---------------------------------------------------------------------------
extern "C" void kernel_launch(void* const* d_in, const int* in_sizes, int n_in,
                              void* d_out, int out_size, void* d_ws, size_t ws_size,
                              hipStream_t stream) {
    const float* x    = (const float*)d_in[0];
    const float* ln1w = (const float*)d_in[1];
    const float* ln1b = (const float*)d_in[2];
    const float* WQ   = (const float*)d_in[3];
    const float* WK   = (const float*)d_in[4];
    const float* WV   = (const float*)d_in[5];
    const float* ln2w = (const float*)d_in[6];
    const float* ln2b = (const float*)d_in[7];
    const float* W1   = (const float*)d_in[8];
    const float* b1   = (const float*)d_in[9];
    const float* W2   = (const float*)d_in[10];
    const float* b2   = (const float*)d_in[11];
    float* out = (float*)d_out;

    char* p = (char*)d_ws;
    u16* norm   = (u16*)p;   p += (size_t)8192 * 256 * 2;
    u16* BtQKV  = (u16*)p;   p += (size_t)768 * 256 * 2;
    u16* W1t    = (u16*)p;   p += (size_t)256 * 256 * 2;
    u16* W2t    = (u16*)p;   p += (size_t)256 * 256 * 2;
    u16* Qb     = (u16*)p;   p += (size_t)NHT * SEQ * 64 * 2;
    u16* Kb     = (u16*)p;   p += (size_t)NHT * SEQ * 64 * 2;
    u16* Vb     = (u16*)p;   p += (size_t)NHT * SEQ * 64 * 2;
    float* Dsum = (float*)p; p += (size_t)NHT * SEQ * 4;
    u16* Vt     = (u16*)p;   p += (size_t)NHT * SEQ * 64 * 2;
    float* acat = (float*)p; p += (size_t)8192 * 256 * 4;
    u16* h2     = (u16*)p;   p += (size_t)8192 * 256 * 2;
    u16* tbuf   = (u16*)p;   p += (size_t)8192 * 256 * 2;
    float* osc  = (float*)p; p += (size_t)8192 * 256 * 4;

    k_pack<<<1280, 256, 0, stream>>>(WQ, WK, WV, W1, W2, BtQKV, W1t, W2t);
    k_ln1<<<dim3(128, 2), 256, 0, stream>>>(x, ln1w, ln1b, norm);
    k_qkv<<<dim3(6, 64), 256, 0, stream>>>(norm, BtQKV, Qb, Kb, Vb);
    k_pass1<<<dim3(32, 8), 256, 0, stream>>>(Qb, Kb, Dsum);
    k_scaleV<<<dim3(64, 8), 256, 0, stream>>>(Vb, Dsum, Vt);
    k_pass2<<<dim3(32, 8), 256, 0, stream>>>(Qb, Kb, Vt, acat);
    k_ln2<<<dim3(128, 2), 256, 0, stream>>>(x, acat, ln2w, ln2b, h2);
    k_mlp1<<<dim3(2, 64), 256, 0, stream>>>(h2, W1t, b1, tbuf);
    k_mlp2<<<dim3(2, 64), 256, 0, stream>>>(tbuf, W2t, b2, acat, osc);
    k_trout<<<dim3(64, 4, 2), 256, 0, stream>>>(osc, out);
}

// Round 2
// 412.897 us; speedup vs baseline: 1.1438x; 1.1438x over previous
//
#include <hip/hip_runtime.h>
#include <math.h>

#define SEQ 4096
#define CH  256
#define NHT 8      // N * HEADS
#define DHD 64

using bf16x8 = __attribute__((ext_vector_type(8))) short;
using f32x4  = __attribute__((ext_vector_type(4))) float;
typedef unsigned short u16;
typedef unsigned int   u32;

__device__ __forceinline__ u16 f2bf(float f) {
    u32 u = __float_as_uint(f);
    u = (u + 0x7fffu + ((u >> 16) & 1u)) >> 16;
    return (u16)u;
}
__device__ __forceinline__ float bf2f(u16 h) {
    return __uint_as_float(((u32)h) << 16);
}

// ---------------------------------------------------------------------------
// Core: 128x128 NT GEMM tile (used by qkv/mlp1/mlp2). A [128][K] row-major
// bf16 (lda), Bt [128 out-cols][K] row-major bf16 (ldb). 4 waves, 64x64
// quadrants. acc C-layout: C[wr+i*16+quad*4+r][wc+j*16+(lane&15)].
// ---------------------------------------------------------------------------
__device__ __forceinline__ void mm128(const u16* __restrict__ Arow, int lda,
                                      const u16* __restrict__ Brow, int ldb,
                                      int K, u16 (*lA)[40], u16 (*lB)[40],
                                      f32x4 acc[4][4])
{
    const int t    = threadIdx.x;
    const int wave = t >> 6, lane = t & 63;
    const int quad = lane >> 4, l16 = lane & 15;
    const int wr = (wave >> 1) * 64, wc = (wave & 1) * 64;
    const int lrow = t >> 2;
    const int lcol = (t & 3) * 8;

    for (int kt = 0; kt < K; kt += 32) {
        *(uint4*)&lA[lrow][lcol]      = *(const uint4*)&Arow[lrow * lda + kt + lcol];
        *(uint4*)&lA[lrow + 64][lcol] = *(const uint4*)&Arow[(lrow + 64) * lda + kt + lcol];
        *(uint4*)&lB[lrow][lcol]      = *(const uint4*)&Brow[lrow * ldb + kt + lcol];
        *(uint4*)&lB[lrow + 64][lcol] = *(const uint4*)&Brow[(lrow + 64) * ldb + kt + lcol];
        __syncthreads();
        bf16x8 af[4], bf[4];
        #pragma unroll
        for (int i = 0; i < 4; i++) af[i] = *(const bf16x8*)&lA[wr + i * 16 + l16][quad * 8];
        #pragma unroll
        for (int j = 0; j < 4; j++) bf[j] = *(const bf16x8*)&lB[wc + j * 16 + l16][quad * 8];
        #pragma unroll
        for (int i = 0; i < 4; i++)
            #pragma unroll
            for (int j = 0; j < 4; j++)
                acc[i][j] = __builtin_amdgcn_mfma_f32_16x16x32_bf16(af[i], bf[j], acc[i][j], 0, 0, 0);
        __syncthreads();
    }
}

// ---------------------------------------------------------------------------
__global__ __launch_bounds__(256) void k_pack(const float* __restrict__ WQ,
                                              const float* __restrict__ WK,
                                              const float* __restrict__ WV,
                                              const float* __restrict__ W1,
                                              const float* __restrict__ W2,
                                              u16* __restrict__ BtQKV,
                                              u16* __restrict__ W1t,
                                              u16* __restrict__ W2t)
{
    int id = blockIdx.x * 256 + threadIdx.x;
    if (id < 768 * 256) {
        int j = id >> 8, c = id & 255;
        int which = j >> 8, h = (j >> 6) & 3, d = j & 63;
        const float* W = (which == 0) ? WQ : (which == 1) ? WK : WV;
        BtQKV[id] = f2bf(W[(h * 256 + c) * 64 + d]);
    } else if (id < 768 * 256 + 65536) {
        int jj = id - 768 * 256;
        int j = jj >> 8, c = jj & 255;
        W1t[jj] = f2bf(W1[c * 256 + j]);
    } else if (id < 768 * 256 + 2 * 65536) {
        int jj = id - 768 * 256 - 65536;
        int j = jj >> 8, c = jj & 255;
        W2t[jj] = f2bf(W2[c * 256 + j]);
    }
}

// ---------------------------------------------------------------------------
__global__ __launch_bounds__(256) void k_ln1(const float* __restrict__ x,
                                             const float* __restrict__ w,
                                             const float* __restrict__ b,
                                             u16* __restrict__ norm)
{
    __shared__ float tile[32][257];
    __shared__ float mu[32], rs[32];
    int n = blockIdx.y, s0 = blockIdx.x * 32;
    int t = threadIdx.x;
    int sl = t & 31, cg = t >> 5;
    for (int cc = 0; cc < 256; cc += 8) {
        int c = cc + cg;
        tile[sl][c] = x[(n * 256 + c) * SEQ + s0 + sl];
    }
    __syncthreads();
    int wv = t >> 6, l = t & 63;
    for (int rr = 0; rr < 8; rr++) {
        int s = wv * 8 + rr;
        float a0 = tile[s][l], a1 = tile[s][l + 64], a2 = tile[s][l + 128], a3 = tile[s][l + 192];
        float sm = a0 + a1 + a2 + a3;
        float sq = a0 * a0 + a1 * a1 + a2 * a2 + a3 * a3;
        for (int off = 32; off; off >>= 1) { sm += __shfl_xor(sm, off); sq += __shfl_xor(sq, off); }
        if (l == 0) {
            float m = sm * (1.f / 256.f);
            mu[s] = m;
            rs[s] = rsqrtf(sq * (1.f / 256.f) - m * m + 1e-5f);
        }
    }
    __syncthreads();
    float ww = w[t & 255], bb = b[t & 255];
    for (int s = 0; s < 32; s++) {
        float v = (tile[s][t] - mu[s]) * rs[s] * ww + bb;
        norm[(n * SEQ + s0 + s) * 256 + t] = f2bf(v);
    }
}

// ---------------------------------------------------------------------------
__global__ __launch_bounds__(256) void k_qkv(const u16* __restrict__ norm,
                                             const u16* __restrict__ Bt,
                                             u16* __restrict__ Qo,
                                             u16* __restrict__ Ko,
                                             u16* __restrict__ Vo)
{
    __shared__ __align__(16) u16 lA[128][40];
    __shared__ __align__(16) u16 lB[128][40];
    int j0 = blockIdx.x * 128, m0 = blockIdx.y * 128;
    f32x4 z = {0.f, 0.f, 0.f, 0.f};
    f32x4 acc[4][4];
    #pragma unroll
    for (int i = 0; i < 4; i++)
        #pragma unroll
        for (int j = 0; j < 4; j++) acc[i][j] = z;
    mm128(norm + (long)m0 * 256, 256, Bt + (long)j0 * 256, 256, 256, lA, lB, acc);
    int t = threadIdx.x, wave = t >> 6, lane = t & 63, quad = lane >> 4, l16 = lane & 15;
    int wr = (wave >> 1) * 64, wc = (wave & 1) * 64;
    #pragma unroll
    for (int i = 0; i < 4; i++)
        #pragma unroll
        for (int j = 0; j < 4; j++) {
            int col = j0 + wc + j * 16 + l16;
            int which = col >> 8, h = (col >> 6) & 3, d = col & 63;
            u16* dst = (which == 0) ? Qo : (which == 1) ? Ko : Vo;
            #pragma unroll
            for (int r = 0; r < 4; r++) {
                int m = m0 + wr + i * 16 + quad * 4 + r;
                int n = m >> 12, s = m & 4095;
                dst[((n * 4 + h) * SEQ + s) * 64 + d] = f2bf(acc[i][j][r]);
            }
        }
}

// ---------------------------------------------------------------------------
// Pass 1: partial column sums D4[qc][nh][k] = sum_{q in chunk} exp(QK^T/64).
// S^T form: A = K rows (k) held in REGISTERS (reused over the whole q loop),
// B = Q rows staged in LDS. Grid (32 k-tiles, 8 nh, 4 q-chunks).
// ---------------------------------------------------------------------------
__global__ __launch_bounds__(256) void k_pass1(const u16* __restrict__ Q,
                                               const u16* __restrict__ Km,
                                               float* __restrict__ D4)
{
    __shared__ __align__(16) u16 lQ[128][72];
    int nh = blockIdx.y, k0 = blockIdx.x * 128, qc = blockIdx.z;
    const u16* Qh = Q + (long)nh * SEQ * 64;
    const u16* Kh = Km + (long)nh * SEQ * 64;
    int t = threadIdx.x, w = t >> 6, lane = t & 63, quad = lane >> 4, l16 = lane & 15;
    // K fragments: wave w owns k rows [k0+w*32, +32): 2 m-subtiles x 2 K-chunks
    bf16x8 Kf[2][2];
    #pragma unroll
    for (int i = 0; i < 2; i++)
        #pragma unroll
        for (int ch = 0; ch < 2; ch++)
            Kf[i][ch] = *(const bf16x8*)&Kh[(k0 + w * 32 + i * 16 + l16) * 64 + ch * 32 + quad * 8];
    f32x4 z = {0.f, 0.f, 0.f, 0.f};
    float Dacc[2][4] = {{0.f, 0.f, 0.f, 0.f}, {0.f, 0.f, 0.f, 0.f}};
    const float C = 0.015625f * 1.44269504088896f;   // log2(e)/64
    for (int q0 = qc * 1024; q0 < qc * 1024 + 1024; q0 += 128) {
        #pragma unroll
        for (int p = 0; p < 4; p++) {
            int idx = t + p * 256;
            int row = idx >> 3, cc = (idx & 7) * 8;
            *(uint4*)&lQ[row][cc] = *(const uint4*)&Qh[(q0 + row) * 64 + cc];
        }
        __syncthreads();
        #pragma unroll
        for (int j = 0; j < 8; j++) {
            bf16x8 b0 = *(const bf16x8*)&lQ[j * 16 + l16][quad * 8];
            bf16x8 b1 = *(const bf16x8*)&lQ[j * 16 + l16][32 + quad * 8];
            #pragma unroll
            for (int i = 0; i < 2; i++) {
                f32x4 acc = z;
                acc = __builtin_amdgcn_mfma_f32_16x16x32_bf16(Kf[i][0], b0, acc, 0, 0, 0);
                acc = __builtin_amdgcn_mfma_f32_16x16x32_bf16(Kf[i][1], b1, acc, 0, 0, 0);
                #pragma unroll
                for (int r = 0; r < 4; r++) Dacc[i][r] += exp2f(acc[r] * C);
            }
        }
        __syncthreads();
    }
    // reduce over the 16 q-lanes (sum over q), lane l16==0 stores
    #pragma unroll
    for (int i = 0; i < 2; i++)
        #pragma unroll
        for (int r = 0; r < 4; r++) {
            float v = Dacc[i][r];
            v += __shfl_xor(v, 1); v += __shfl_xor(v, 2);
            v += __shfl_xor(v, 4); v += __shfl_xor(v, 8);
            if (l16 == 0)
                D4[((long)(qc * NHT + nh)) * SEQ + k0 + w * 32 + i * 16 + quad * 4 + r] = v;
        }
}

// ---------------------------------------------------------------------------
// Scale+transpose V: Vt[nh][d][k] = V[nh][k][d] / D[nh][k], D = sum of 4
// pass-1 partials.
// ---------------------------------------------------------------------------
__global__ __launch_bounds__(256) void k_scaleV(const u16* __restrict__ V,
                                                const float* __restrict__ D4,
                                                u16* __restrict__ Vt)
{
    __shared__ float tile[64][65];
    int nh = blockIdx.y, k0 = blockIdx.x * 64;
    int t = threadIdx.x;
    int d = t & 63, kk = t >> 6;
    const u16* Vh = V + (long)nh * SEQ * 64;
    for (int p = 0; p < 16; p++) {
        int k = p * 4 + kk;
        float Dv = D4[((long)(0 * NHT + nh)) * SEQ + k0 + k]
                 + D4[((long)(1 * NHT + nh)) * SEQ + k0 + k]
                 + D4[((long)(2 * NHT + nh)) * SEQ + k0 + k]
                 + D4[((long)(3 * NHT + nh)) * SEQ + k0 + k];
        tile[k][d] = bf2f(Vh[(k0 + k) * 64 + d]) * (1.f / Dv);
    }
    __syncthreads();
    int k2 = t & 63, d4 = t >> 6;
    u16* Vth = Vt + (long)nh * 64 * SEQ;
    for (int p = 0; p < 16; p++) {
        int dd = p * 4 + d4;
        Vth[dd * SEQ + k0 + k2] = f2bf(tile[k2][dd]);
    }
}

// ---------------------------------------------------------------------------
// Pass 2: attn = P @ (V/D), P = exp(QK^T/64). S^T trick: per k-tile, compute
// ST = K·Q^T (A = K from LDS, B = Q from registers) so the C-layout lets each
// lane pack 4 consecutive-k P values into ONE ds_write_b64 to lP[q][k].
// PV then reads lP[q][k] as clean b128 A-frags; V^T B-frags come straight
// from global (L2-resident). 2 barriers per k-tile. Waves split k-rows for
// ST, q-rows for PV.
// ---------------------------------------------------------------------------
__global__ __launch_bounds__(256) void k_pass2(const u16* __restrict__ Q,
                                               const u16* __restrict__ Km,
                                               const u16* __restrict__ Vt,
                                               float* __restrict__ attn_cat)
{
    __shared__ __align__(16) u16 lK[128][72];
    __shared__ __align__(16) u16 lP[64][136];
    int nh = blockIdx.y, q0 = blockIdx.x * 64;
    int n = nh >> 2, h = nh & 3;
    const u16* Qh = Q + (long)nh * SEQ * 64;
    const u16* Kh = Km + (long)nh * SEQ * 64;
    const u16* Vh = Vt + (long)nh * 64 * SEQ;
    int t = threadIdx.x, w = t >> 6, lane = t & 63, quad = lane >> 4, l16 = lane & 15;
    // Q fragments for the whole 64-q tile, in registers (reused all k-tiles)
    bf16x8 Qf[4][2];
    #pragma unroll
    for (int j = 0; j < 4; j++)
        #pragma unroll
        for (int ch = 0; ch < 2; ch++)
            Qf[j][ch] = *(const bf16x8*)&Qh[(q0 + j * 16 + l16) * 64 + ch * 32 + quad * 8];
    f32x4 z = {0.f, 0.f, 0.f, 0.f};
    f32x4 accO[4];
    #pragma unroll
    for (int jd = 0; jd < 4; jd++) accO[jd] = z;
    const float C = 0.015625f * 1.44269504088896f;

    for (int k0 = 0; k0 < SEQ; k0 += 128) {
        #pragma unroll
        for (int p = 0; p < 4; p++) {
            int idx = t + p * 256;
            int row = idx >> 3, cc = (idx & 7) * 8;
            *(uint4*)&lK[row][cc] = *(const uint4*)&Kh[(k0 + row) * 64 + cc];
        }
        __syncthreads();
        // ST: wave w computes k rows [w*32, w*32+32) x all 64 q
        #pragma unroll
        for (int i = 0; i < 2; i++) {
            bf16x8 a0 = *(const bf16x8*)&lK[w * 32 + i * 16 + l16][quad * 8];
            bf16x8 a1 = *(const bf16x8*)&lK[w * 32 + i * 16 + l16][32 + quad * 8];
            #pragma unroll
            for (int j = 0; j < 4; j++) {
                f32x4 acc = z;
                acc = __builtin_amdgcn_mfma_f32_16x16x32_bf16(a0, Qf[j][0], acc, 0, 0, 0);
                acc = __builtin_amdgcn_mfma_f32_16x16x32_bf16(a1, Qf[j][1], acc, 0, 0, 0);
                u16 p0 = f2bf(exp2f(acc[0] * C));
                u16 p1 = f2bf(exp2f(acc[1] * C));
                u16 p2 = f2bf(exp2f(acc[2] * C));
                u16 p3 = f2bf(exp2f(acc[3] * C));
                uint2 pk;
                pk.x = (u32)p0 | ((u32)p1 << 16);
                pk.y = (u32)p2 | ((u32)p3 << 16);
                *(uint2*)&lP[j * 16 + l16][w * 32 + i * 16 + quad * 4] = pk;
            }
        }
        __syncthreads();
        // PV: wave w owns q rows [w*16, w*16+16)
        #pragma unroll
        for (int kc = 0; kc < 4; kc++) {
            bf16x8 pa = *(const bf16x8*)&lP[w * 16 + l16][kc * 32 + quad * 8];
            #pragma unroll
            for (int jd = 0; jd < 4; jd++) {
                bf16x8 vb = *(const bf16x8*)&Vh[(jd * 16 + l16) * SEQ + k0 + kc * 32 + quad * 8];
                accO[jd] = __builtin_amdgcn_mfma_f32_16x16x32_bf16(pa, vb, accO[jd], 0, 0, 0);
            }
        }
        // next-iter lK staging is ordered by barrier 1; lP overwrite by barrier 1 too
    }
    #pragma unroll
    for (int jd = 0; jd < 4; jd++)
        #pragma unroll
        for (int r = 0; r < 4; r++) {
            int s = q0 + w * 16 + quad * 4 + r;
            int c = h * 64 + jd * 16 + l16;
            attn_cat[((long)n * SEQ + s) * 256 + c] = accO[jd][r];
        }
}

// ---------------------------------------------------------------------------
__global__ __launch_bounds__(256) void k_ln2(const float* __restrict__ x,
                                             const float* __restrict__ attn_cat,
                                             const float* __restrict__ w,
                                             const float* __restrict__ b,
                                             u16* __restrict__ h2)
{
    __shared__ float tile[32][257];
    __shared__ float mu[32], rs[32];
    int n = blockIdx.y, s0 = blockIdx.x * 32;
    int t = threadIdx.x;
    int sl = t & 31, cg = t >> 5;
    for (int cc = 0; cc < 256; cc += 8) {
        int c = cc + cg;
        tile[sl][c] = x[(n * 256 + c) * SEQ + s0 + sl];
    }
    __syncthreads();
    for (int s = 0; s < 32; s++)
        tile[s][t] += attn_cat[((long)n * SEQ + s0 + s) * 256 + t];
    __syncthreads();
    int wv = t >> 6, l = t & 63;
    for (int rr = 0; rr < 8; rr++) {
        int s = wv * 8 + rr;
        float a0 = tile[s][l], a1 = tile[s][l + 64], a2 = tile[s][l + 128], a3 = tile[s][l + 192];
        float sm = a0 + a1 + a2 + a3;
        float sq = a0 * a0 + a1 * a1 + a2 * a2 + a3 * a3;
        for (int off = 32; off; off >>= 1) { sm += __shfl_xor(sm, off); sq += __shfl_xor(sq, off); }
        if (l == 0) {
            float m = sm * (1.f / 256.f);
            mu[s] = m;
            rs[s] = rsqrtf(sq * (1.f / 256.f) - m * m + 1e-5f);
        }
    }
    __syncthreads();
    float ww = w[t], bb = b[t];
    for (int s = 0; s < 32; s++) {
        float v = (tile[s][t] - mu[s]) * rs[s] * ww + bb;
        h2[((long)n * SEQ + s0 + s) * 256 + t] = f2bf(v);
    }
}

// ---------------------------------------------------------------------------
__global__ __launch_bounds__(256) void k_mlp1(const u16* __restrict__ h2,
                                              const u16* __restrict__ W1t,
                                              const float* __restrict__ b1,
                                              u16* __restrict__ tbuf)
{
    __shared__ __align__(16) u16 lA[128][40];
    __shared__ __align__(16) u16 lB[128][40];
    int j0 = blockIdx.x * 128, m0 = blockIdx.y * 128;
    f32x4 z = {0.f, 0.f, 0.f, 0.f};
    f32x4 acc[4][4];
    #pragma unroll
    for (int i = 0; i < 4; i++)
        #pragma unroll
        for (int j = 0; j < 4; j++) acc[i][j] = z;
    mm128(h2 + (long)m0 * 256, 256, W1t + (long)j0 * 256, 256, 256, lA, lB, acc);
    int t = threadIdx.x, wave = t >> 6, lane = t & 63, quad = lane >> 4, l16 = lane & 15;
    int wr = (wave >> 1) * 64, wc = (wave & 1) * 64;
    #pragma unroll
    for (int i = 0; i < 4; i++)
        #pragma unroll
        for (int j = 0; j < 4; j++) {
            int col = j0 + wc + j * 16 + l16;
            float bj = b1[col];
            #pragma unroll
            for (int r = 0; r < 4; r++) {
                int m = m0 + wr + i * 16 + quad * 4 + r;
                float v = acc[i][j][r] + bj;
                float g = 0.5f * v * (1.f + erff(v * 0.70710678118f));
                tbuf[(long)m * 256 + col] = f2bf(g);
            }
        }
}

// ---------------------------------------------------------------------------
__global__ __launch_bounds__(256) void k_mlp2(const u16* __restrict__ tbuf,
                                              const u16* __restrict__ W2t,
                                              const float* __restrict__ b2,
                                              const float* __restrict__ attn_cat,
                                              float* __restrict__ osc)
{
    __shared__ __align__(16) u16 lA[128][40];
    __shared__ __align__(16) u16 lB[128][40];
    int j0 = blockIdx.x * 128, m0 = blockIdx.y * 128;
    f32x4 z = {0.f, 0.f, 0.f, 0.f};
    f32x4 acc[4][4];
    #pragma unroll
    for (int i = 0; i < 4; i++)
        #pragma unroll
        for (int j = 0; j < 4; j++) acc[i][j] = z;
    mm128(tbuf + (long)m0 * 256, 256, W2t + (long)j0 * 256, 256, 256, lA, lB, acc);
    int t = threadIdx.x, wave = t >> 6, lane = t & 63, quad = lane >> 4, l16 = lane & 15;
    int wr = (wave >> 1) * 64, wc = (wave & 1) * 64;
    #pragma unroll
    for (int i = 0; i < 4; i++)
        #pragma unroll
        for (int j = 0; j < 4; j++) {
            int col = j0 + wc + j * 16 + l16;
            float bj = b2[col];
            #pragma unroll
            for (int r = 0; r < 4; r++) {
                int m = m0 + wr + i * 16 + quad * 4 + r;
                osc[(long)m * 256 + col] = acc[i][j][r] + bj + attn_cat[(long)m * 256 + col];
            }
        }
}

// ---------------------------------------------------------------------------
__global__ __launch_bounds__(256) void k_trout(const float* __restrict__ osc,
                                               float* __restrict__ out)
{
    __shared__ float tile[64][65];
    int n = blockIdx.z, c0 = blockIdx.y * 64, s0 = blockIdx.x * 64;
    int t = threadIdx.x;
    int cc = t & 63, s4 = t >> 6;
    for (int p = 0; p < 16; p++) {
        int s = p * 4 + s4;
        tile[s][cc] = osc[((long)n * SEQ + s0 + s) * 256 + c0 + cc];
    }
    __syncthreads();
    int ss = t & 63, c4 = t >> 6;
    for (int p = 0; p < 16; p++) {
        int c = p * 4 + c4;
        out[((long)n * 256 + c0 + c) * SEQ + s0 + ss] = tile[ss][c];
    }
}

// ---------------------------------------------------------------------------
extern "C" void kernel_launch(void* const* d_in, const int* in_sizes, int n_in,
                              void* d_out, int out_size, void* d_ws, size_t ws_size,
                              hipStream_t stream) {
    const float* x    = (const float*)d_in[0];
    const float* ln1w = (const float*)d_in[1];
    const float* ln1b = (const float*)d_in[2];
    const float* WQ   = (const float*)d_in[3];
    const float* WK   = (const float*)d_in[4];
    const float* WV   = (const float*)d_in[5];
    const float* ln2w = (const float*)d_in[6];
    const float* ln2b = (const float*)d_in[7];
    const float* W1   = (const float*)d_in[8];
    const float* b1   = (const float*)d_in[9];
    const float* W2   = (const float*)d_in[10];
    const float* b2   = (const float*)d_in[11];
    float* out = (float*)d_out;

    char* p = (char*)d_ws;
    u16* norm   = (u16*)p;   p += (size_t)8192 * 256 * 2;
    u16* BtQKV  = (u16*)p;   p += (size_t)768 * 256 * 2;
    u16* W1t    = (u16*)p;   p += (size_t)256 * 256 * 2;
    u16* W2t    = (u16*)p;   p += (size_t)256 * 256 * 2;
    u16* Qb     = (u16*)p;   p += (size_t)NHT * SEQ * 64 * 2;
    u16* Kb     = (u16*)p;   p += (size_t)NHT * SEQ * 64 * 2;
    u16* Vb     = (u16*)p;   p += (size_t)NHT * SEQ * 64 * 2;
    float* D4   = (float*)p; p += (size_t)4 * NHT * SEQ * 4;
    u16* Vt     = (u16*)p;   p += (size_t)NHT * SEQ * 64 * 2;
    float* acat = (float*)p; p += (size_t)8192 * 256 * 4;
    u16* h2     = (u16*)p;   p += (size_t)8192 * 256 * 2;
    u16* tbuf   = (u16*)p;   p += (size_t)8192 * 256 * 2;
    float* osc  = (float*)p; p += (size_t)8192 * 256 * 4;

    k_pack<<<1280, 256, 0, stream>>>(WQ, WK, WV, W1, W2, BtQKV, W1t, W2t);
    k_ln1<<<dim3(128, 2), 256, 0, stream>>>(x, ln1w, ln1b, norm);
    k_qkv<<<dim3(6, 64), 256, 0, stream>>>(norm, BtQKV, Qb, Kb, Vb);
    k_pass1<<<dim3(32, 8, 4), 256, 0, stream>>>(Qb, Kb, D4);
    k_scaleV<<<dim3(64, 8), 256, 0, stream>>>(Vb, D4, Vt);
    k_pass2<<<dim3(64, 8), 256, 0, stream>>>(Qb, Kb, Vt, acat);
    k_ln2<<<dim3(128, 2), 256, 0, stream>>>(x, acat, ln2w, ln2b, h2);
    k_mlp1<<<dim3(2, 64), 256, 0, stream>>>(h2, W1t, b1, tbuf);
    k_mlp2<<<dim3(2, 64), 256, 0, stream>>>(tbuf, W2t, b2, acat, osc);
    k_trout<<<dim3(64, 4, 2), 256, 0, stream>>>(osc, out);
}